// Round 1
// baseline (38.935 us; speedup 1.0000x reference)
//
#include <hip/hip_runtime.h>

// Problem: x:[B=64,S=2048,K=256] f32, W:[K=256,D=512] f32
// out[b,d] = mean_s(x) @ W  -> [64,512] f32
// Strategy: seq-reduce x (128 MiB read, HBM-bound) then tiny GEMM.

#define BB 64
#define SS 2048
#define KK 256
#define DD 512
#define CHUNKS 32
#define ROWS_PER_CHUNK (SS / CHUNKS)  // 64

// Stage A: partial sums over s. One block per (b, chunk).
// 256 threads = 64 lanes across K (float4 each) x 4 rows in s.
__global__ __launch_bounds__(256) void partial_sum_kernel(const float* __restrict__ x,
                                                          float* __restrict__ part) {
    const int blk = blockIdx.x;          // b * CHUNKS + c
    const int b  = blk / CHUNKS;
    const int c  = blk % CHUNKS;
    const int t  = threadIdx.x;
    const int tx = t & 63;               // float4 index across K (64*4 = 256)
    const int ty = t >> 6;               // 0..3

    const float4* xp = (const float4*)(x + (size_t)b * SS * KK + (size_t)c * ROWS_PER_CHUNK * KK);

    float4 acc = make_float4(0.f, 0.f, 0.f, 0.f);
    #pragma unroll 4
    for (int s = ty; s < ROWS_PER_CHUNK; s += 4) {
        float4 v = xp[(size_t)s * (KK / 4) + tx];
        acc.x += v.x; acc.y += v.y; acc.z += v.z; acc.w += v.w;
    }

    __shared__ float4 smem[4][64];
    smem[ty][tx] = acc;
    __syncthreads();

    if (ty == 0) {
        float4 a0 = smem[0][tx], a1 = smem[1][tx], a2 = smem[2][tx], a3 = smem[3][tx];
        float4 r;
        r.x = (a0.x + a1.x) + (a2.x + a3.x);
        r.y = (a0.y + a1.y) + (a2.y + a3.y);
        r.z = (a0.z + a1.z) + (a2.z + a3.z);
        r.w = (a0.w + a1.w) + (a2.w + a3.w);
        ((float4*)(part + (size_t)b * CHUNKS * KK + (size_t)c * KK))[tx] = r;
    }
}

// Stage B: per-b block. Reduce CHUNKS partials -> x_mean in LDS, then dot with W.
__global__ __launch_bounds__(256) void finish_kernel(const float* __restrict__ part,
                                                     const float* __restrict__ w,
                                                     float* __restrict__ out) {
    const int b = blockIdx.x;
    const int t = threadIdx.x;           // 0..255

    __shared__ float xm[KK];
    float s = 0.f;
    const float* pp = part + (size_t)b * CHUNKS * KK + t;
    #pragma unroll
    for (int c = 0; c < CHUNKS; ++c) s += pp[(size_t)c * KK];
    xm[t] = s * (1.0f / SS);
    __syncthreads();

    // Each thread computes out[b, 2t] and out[b, 2t+1] via float2 on W rows.
    float2 acc = make_float2(0.f, 0.f);
    const float2* w2 = (const float2*)w;
    #pragma unroll 8
    for (int k = 0; k < KK; ++k) {
        const float xv = xm[k];                    // LDS broadcast, conflict-free
        const float2 wv = w2[(size_t)k * (DD / 2) + t];
        acc.x += xv * wv.x;
        acc.y += xv * wv.y;
    }
    ((float2*)out)[(size_t)b * (DD / 2) + t] = acc;
}

extern "C" void kernel_launch(void* const* d_in, const int* in_sizes, int n_in,
                              void* d_out, int out_size, void* d_ws, size_t ws_size,
                              hipStream_t stream) {
    const float* x = (const float*)d_in[0];
    const float* w = (const float*)d_in[1];
    float* out  = (float*)d_out;
    float* part = (float*)d_ws;   // B*CHUNKS*K floats = 2 MiB

    partial_sum_kernel<<<BB * CHUNKS, 256, 0, stream>>>(x, part);
    finish_kernel<<<BB, 256, 0, stream>>>(part, w, out);
}

// Round 3
// 33.843 us; speedup vs baseline: 1.1504x; 1.1504x over previous
//
#include <hip/hip_runtime.h>

// Problem: x:[B=64,S=2048,K=256] f32, W:[K=256,D=512] f32
// out[b,d] = mean_s(x) @ W  -> [64,512] f32
// Two kernels: stage A seq-reduces x into [B,CHUNKS,K] partials (HBM-bound,
// 128 MiB read); stage B (512 blocks, split-k 8) finishes mean + tiny GEMM.

typedef float f32x4 __attribute__((ext_vector_type(4)));

#define BB 64
#define SS 2048
#define KK 256
#define DD 512
#define CHUNKS 32
#define RPC (SS / CHUNKS)  // 64 rows per chunk

// Stage A: one block per (b, chunk). 256 threads = 64 f32x4 lanes across K
// x 4 rows in s. Nontemporal: x is streamed exactly once.
__global__ __launch_bounds__(256) void partial_sum_kernel(const float* __restrict__ x,
                                                          float* __restrict__ part) {
    const int blk = blockIdx.x;          // b * CHUNKS + c
    const int b  = blk >> 5;
    const int c  = blk & 31;
    const int t  = threadIdx.x;
    const int tx = t & 63;               // f32x4 index across K (64*4 = 256)
    const int ty = t >> 6;               // 0..3

    const f32x4* xp = (const f32x4*)(x + (size_t)b * SS * KK + (size_t)c * RPC * KK) + tx;

    f32x4 acc = {0.f, 0.f, 0.f, 0.f};
    #pragma unroll
    for (int i = 0; i < RPC / 4; ++i) {
        f32x4 v = __builtin_nontemporal_load(xp + (size_t)(i * 4 + ty) * (KK / 4));
        acc += v;
    }

    __shared__ f32x4 smem[4][64];
    smem[ty][tx] = acc;
    __syncthreads();

    if (ty == 0) {
        f32x4 r = (smem[0][tx] + smem[1][tx]) + (smem[2][tx] + smem[3][tx]);
        ((f32x4*)(part + ((size_t)b * CHUNKS + c) * KK))[tx] = r;
    }
}

// Stage B: 8 blocks per b. Block (b,dq): 64 output cols (32 float2),
// split-k 8-way across thread groups, LDS reduce, store.
__global__ __launch_bounds__(256) void finish_kernel(const float* __restrict__ part,
                                                     const float* __restrict__ w,
                                                     float* __restrict__ out) {
    const int b  = blockIdx.x >> 3;
    const int dq = blockIdx.x & 7;
    const int t  = threadIdx.x;          // 0..255

    __shared__ float xm[KK];
    {
        float s = 0.f;
        const float* pp = part + (size_t)b * CHUNKS * KK + t;
        #pragma unroll
        for (int c = 0; c < CHUNKS; ++c) s += pp[c * KK];
        xm[t] = s * (1.0f / SS);
    }
    __syncthreads();

    const int col2 = dq * 32 + (t & 31); // float2 column in [0, 256)
    const int kg   = t >> 5;             // k-group 0..7, 32 k's each
    const float2* w2 = (const float2*)w;

    float2 acc = make_float2(0.f, 0.f);
    #pragma unroll
    for (int kk = 0; kk < 32; ++kk) {
        const int k = kg * 32 + kk;
        const float  xv = xm[k];         // per-half-wave broadcast, conflict-free
        const float2 wv = w2[(size_t)k * (DD / 2) + col2];
        acc.x += xv * wv.x;
        acc.y += xv * wv.y;
    }

    __shared__ float2 red[8][32];
    if (kg) red[kg][t & 31] = acc;
    __syncthreads();
    if (kg == 0) {
        #pragma unroll
        for (int g = 1; g < 8; ++g) {
            acc.x += red[g][t].x;
            acc.y += red[g][t].y;
        }
        ((float2*)out)[(size_t)b * (DD / 2) + col2] = acc;
    }
}

extern "C" void kernel_launch(void* const* d_in, const int* in_sizes, int n_in,
                              void* d_out, int out_size, void* d_ws, size_t ws_size,
                              hipStream_t stream) {
    const float* x = (const float*)d_in[0];
    const float* w = (const float*)d_in[1];
    float* out  = (float*)d_out;
    float* part = (float*)d_ws;   // B*CHUNKS*K floats = 2 MiB

    partial_sum_kernel<<<BB * CHUNKS, 256, 0, stream>>>(x, part);
    finish_kernel<<<BB * 8, 256, 0, stream>>>(part, w, out);
}